// Round 6
// baseline (492.670 us; speedup 1.0000x reference)
//
#include <hip/hip_runtime.h>
#include <hip/hip_bf16.h>

#define BB 8
#define TSEQ 8192
#define DDIM 512
#define NH 4
#define HDIM 128
#define NP 24
#define NPAD 32
#define NTOPK 12
#define NCHUNK 32
#define TCHUNK 256
#define TTILE 32
#define NTILES 8

typedef _Float16 half8_t __attribute__((ext_vector_type(8)));
typedef _Float16 half4_t __attribute__((ext_vector_type(4)));
typedef _Float16 half2_t __attribute__((ext_vector_type(2)));
typedef float f32x4_t __attribute__((ext_vector_type(4)));

#define MFMA(a, b, c) __builtin_amdgcn_mfma_f32_16x16x32_f16((a), (b), (c), 0, 0, 0)

// Barrier that does NOT drain vmcnt: LDS ordering only. Keeps global loads
// (x prefetch) in flight across phase barriers so HBM latency hides under MFMA.
#define WGBAR() do { asm volatile("s_waitcnt lgkmcnt(0)" ::: "memory"); \
                     __builtin_amdgcn_s_barrier(); } while (0)

// ws layout (float units):
// qhs    @ 0        (12288)   [H][P][HD] f32, l2norm + 1/TEMP folded
// ml     @ 12288    (65536)   [B][H][32][32][2] f32
// xbar   @ 77824    (8388608 f32 = 16777216 f16) [B][H][32][32][512] f16
// pt     @ 8466432  (98304)   [B][P][D] f32
// wk16   @ 8564736  (262144 f16)  [512][512] f16
// wqk16  @ 8695808  (65536 f16)   [h*32+p][512] f16
// total 8728576 f32 = 34.9 MB

// ---------------- Qh precompute ----
__global__ __launch_bounds__(256) void qh_kernel(
    const float* __restrict__ proto, const float* __restrict__ Wq, float* __restrict__ qhs)
{
  const int p = blockIdx.x, tid = threadIdx.x;
  __shared__ float prow[DDIM];
  __shared__ float qp[DDIM];
  __shared__ float np[NH][8];
  __shared__ float nb[NH];
  prow[tid] = proto[(size_t)p * DDIM + tid];
  prow[tid + 256] = proto[(size_t)p * DDIM + tid + 256];
  __syncthreads();
#pragma unroll
  for (int i = 0; i < 2; ++i) {
    int dd = tid + i * 256;
    const float4* w4 = reinterpret_cast<const float4*>(Wq + (size_t)dd * DDIM);
    const float4* p4 = reinterpret_cast<const float4*>(prow);
    float s = 0.f;
    for (int d = 0; d < 128; ++d) {
      float4 av = p4[d], bv = w4[d];
      s += av.x * bv.x + av.y * bv.y + av.z * bv.z + av.w * bv.w;
    }
    qp[dd] = s;
  }
  __syncthreads();
  {
    int hh = tid >> 3, pr = tid & 7;
    if (hh < NH) {
      float s = 0.f;
      for (int k = 0; k < 16; ++k) { float v = qp[hh * HDIM + pr * 16 + k]; s += v * v; }
      np[hh][pr] = s;
    }
  }
  __syncthreads();
  if (tid < NH) {
    float s = 0.f;
    for (int k = 0; k < 8; ++k) s += np[tid][k];
    nb[tid] = 1.f / (fmaxf(sqrtf(s), 1e-12f) * 0.07f);
  }
  __syncthreads();
#pragma unroll
  for (int i = 0; i < 2; ++i) {
    int dd = tid + i * 256;
    int hh = dd >> 7, jj = dd & 127;
    qhs[((size_t)hh * NP + p) * HDIM + jj] = qp[dd] * nb[hh];
  }
}

// ---------------- Wk -> f16 copy ----
__global__ __launch_bounds__(256) void wk16_kernel(
    const float* __restrict__ Wk, _Float16* __restrict__ wk16)
{
  const int row = blockIdx.x, tid = threadIdx.x;
  wk16[(size_t)row * 512 + tid]       = (_Float16)Wk[(size_t)row * 512 + tid];
  wk16[(size_t)row * 512 + tid + 256] = (_Float16)Wk[(size_t)row * 512 + tid + 256];
}

// ---------------- Wqk[h*32+p][d] = sum_j qhs[h][p][j] * Wk[h*128+j][d], f16 ----
__global__ __launch_bounds__(256) void wqk_kernel(
    const float* __restrict__ qhs, const float* __restrict__ Wk, _Float16* __restrict__ wqk16)
{
  const int blk = blockIdx.x, tid = threadIdx.x;
  const int p = blk & 31, h = blk >> 5;
  if (p >= NP) {
    wqk16[((size_t)(h * 32 + p)) * 512 + tid] = (_Float16)0.f;
    wqk16[((size_t)(h * 32 + p)) * 512 + tid + 256] = (_Float16)0.f;
    return;
  }
  __shared__ float qv[HDIM];
  if (tid < HDIM) qv[tid] = qhs[((size_t)h * NP + p) * HDIM + tid];
  __syncthreads();
  float s0 = 0.f, s1 = 0.f;
  for (int j = 0; j < HDIM; ++j) {
    float q = qv[j];
    const float* wr = Wk + (size_t)(h * 128 + j) * 512;
    s0 += q * wr[tid];
    s1 += q * wr[tid + 256];
  }
  wqk16[((size_t)(h * 32 + p)) * 512 + tid] = (_Float16)s0;
  wqk16[((size_t)(h * 32 + p)) * 512 + tid + 256] = (_Float16)s1;
}

// ---------------- fused LN + K/scores MFMA + online softmax + MFMA accumulate ----
// block: 512 thr (8 waves). grid: [b(8)][g2(2)][c(32)]. 2 heads per block.
__global__ __launch_bounds__(512, 2) void attn3(
    const float* __restrict__ x, const float* __restrict__ ln_g, const float* __restrict__ ln_b,
    const _Float16* __restrict__ wk16, const _Float16* __restrict__ wqk16,
    float* __restrict__ ml, _Float16* __restrict__ xbar)
{
  const int tid = threadIdx.x;
  const int w = tid >> 6, l = tid & 63;
  const int g = l >> 4, a = l & 15;
  const int blk = blockIdx.x;
  const int c = blk & 31, g2 = (blk >> 5) & 1, b = blk >> 6;

  __shared__ __align__(16) unsigned char xs_raw[32 * 1040];   // [32 t][520 f16]
  __shared__ __align__(16) unsigned char xt_raw[512 * 72];    // [512 d][36 f16], quad-swizzled
  __shared__ __align__(16) unsigned char wl_raw[64 * 80];     // [64 p][40 f16]
  __shared__ float normp_s[8][32];
  __shared__ float mArr_s[64], lArr_s[64], fbuf_s[64];

  if (tid < 64) { mArr_s[tid] = -1e30f; lArr_s[tid] = 0.f; }

  f32x4_t acc3[4][4];
  const f32x4_t vzero = {0.f, 0.f, 0.f, 0.f};
#pragma unroll
  for (int mA = 0; mA < 4; ++mA)
#pragma unroll
    for (int nt = 0; nt < 4; ++nt) acc3[mA][nt] = vzero;

  float4 gq[2], bq[2];
#pragma unroll
  for (int i = 0; i < 2; ++i) {
    gq[i] = reinterpret_cast<const float4*>(ln_g)[l + 64 * i];
    bq[i] = reinterpret_cast<const float4*>(ln_b)[l + 64 * i];
  }

  const float4* xc4 = reinterpret_cast<const float4*>(x) + ((size_t)(b * TSEQ + c * TCHUNK)) * 128;
  const _Float16* wkbase = wk16 + ((size_t)(g2 * 256 + 32 * w + a)) * 512 + g * 8;
  const _Float16* wqbase = wqk16 + ((size_t)(g2 * 64 + 16 * w + a)) * 512 + g * 8;   // only w<4

  float4 praw[4][2];
#pragma unroll
  for (int tt = 0; tt < 4; ++tt)
#pragma unroll
    for (int i = 0; i < 2; ++i)
      praw[tt][i] = xc4[(size_t)(4 * w + tt) * 128 + l + 64 * i];

  for (int tile = 0; tile < NTILES; ++tile) {
    // ---- LN stats (registers + shuffles only) ----
    float sA[4], sB[4];
#pragma unroll
    for (int tt = 0; tt < 4; ++tt) {
      float4 v0 = praw[tt][0], v1 = praw[tt][1];
      sA[tt] = (v0.x + v0.y) + (v0.z + v0.w) + (v1.x + v1.y) + (v1.z + v1.w);
      sB[tt] = (v0.x * v0.x + v0.y * v0.y) + (v0.z * v0.z + v0.w * v0.w)
             + (v1.x * v1.x + v1.y * v1.y) + (v1.z * v1.z + v1.w * v1.w);
    }
#pragma unroll
    for (int m = 1; m < 64; m <<= 1)
#pragma unroll
      for (int tt = 0; tt < 4; ++tt) { sA[tt] += __shfl_xor(sA[tt], m); sB[tt] += __shfl_xor(sB[tt], m); }
    float muv[4], ivv[4];
#pragma unroll
    for (int tt = 0; tt < 4; ++tt) {
      float mu = sA[tt] * (1.f / 512.f);
      float var = sB[tt] * (1.f / 512.f) - mu * mu;
      muv[tt] = mu; ivv[tt] = rsqrtf(var + 1e-5f);
    }

    WGBAR();   // barA: prev tile's GEMM reads of xs/xt done (LDS only, no vmem drain)

    // ---- normalize, write xs (d-contig) ----
#pragma unroll
    for (int tt = 0; tt < 4; ++tt) {
#pragma unroll
      for (int i = 0; i < 2; ++i) {
        float4 v = praw[tt][i];
        v.x = (v.x - muv[tt]) * ivv[tt] * gq[i].x + bq[i].x;
        v.y = (v.y - muv[tt]) * ivv[tt] * gq[i].y + bq[i].y;
        v.z = (v.z - muv[tt]) * ivv[tt] * gq[i].z + bq[i].z;
        v.w = (v.w - muv[tt]) * ivv[tt] * gq[i].w + bq[i].w;
        praw[tt][i] = v;
        half4_t hx;
        hx[0] = (_Float16)v.x; hx[1] = (_Float16)v.y; hx[2] = (_Float16)v.z; hx[3] = (_Float16)v.w;
        *reinterpret_cast<half4_t*>(xs_raw + (4 * w + tt) * 1040 + 8 * l + 512 * i) = hx;
      }
    }
    // ---- write xt (t-contig half4 per d-row), quad XOR swizzle key=(d>>4)&7 ----
    {
      const float* pf = reinterpret_cast<const float*>(praw);
#pragma unroll
      for (int i = 0; i < 2; ++i)
#pragma unroll
        for (int e = 0; e < 4; ++e) {
          half4_t hv;
          hv[0] = (_Float16)pf[0 * 8 + i * 4 + e];
          hv[1] = (_Float16)pf[1 * 8 + i * 4 + e];
          hv[2] = (_Float16)pf[2 * 8 + i * 4 + e];
          hv[3] = (_Float16)pf[3 * 8 + i * 4 + e];
          int d = 4 * l + 256 * i + e;
          *reinterpret_cast<half4_t*>(xt_raw + d * 72 + 8 * (w ^ ((d >> 4) & 7))) = hv;
        }
    }
    // ---- prefetch next tile: stays in flight across G1..G3 (no vmcnt drain at barriers) ----
    if (tile + 1 < NTILES) {
#pragma unroll
      for (int tt = 0; tt < 4; ++tt)
#pragma unroll
        for (int i = 0; i < 2; ++i)
          praw[tt][i] = xc4[(size_t)((tile + 1) * 32 + 4 * w + tt) * 128 + l + 64 * i];
    }
    WGBAR();   // barB: xs/xt ready

    // ---- G1 (K for norms) + G2 (raw scores, waves 0-3) ----
    f32x4_t kacc[2][2] = {{vzero, vzero}, {vzero, vzero}};
    f32x4_t qacc[2] = {vzero, vzero};
#pragma unroll
    for (int kst = 0; kst < 16; ++kst) {
      half8_t b0 = *reinterpret_cast<const half8_t*>(wkbase + kst * 32);
      half8_t b1 = *reinterpret_cast<const half8_t*>(wkbase + 16 * 512 + kst * 32);
#pragma unroll
      for (int mt = 0; mt < 2; ++mt) {
        half8_t af = *reinterpret_cast<const half8_t*>(xs_raw + (16 * mt + a) * 1040 + kst * 64 + g * 16);
        kacc[mt][0] = MFMA(af, b0, kacc[mt][0]);
        kacc[mt][1] = MFMA(af, b1, kacc[mt][1]);
        if (w < 4) {
          half8_t bq8 = *reinterpret_cast<const half8_t*>(wqbase + kst * 32);
          qacc[mt] = MFMA(af, bq8, qacc[mt]);
        }
      }
    }
    // ---- per-token norm partials ----
    {
      float np2[2][4];
#pragma unroll
      for (int mt = 0; mt < 2; ++mt)
#pragma unroll
        for (int r = 0; r < 4; ++r)
          np2[mt][r] = kacc[mt][0][r] * kacc[mt][0][r] + kacc[mt][1][r] * kacc[mt][1][r];
#pragma unroll
      for (int m = 1; m < 16; m <<= 1)
#pragma unroll
        for (int mt = 0; mt < 2; ++mt)
#pragma unroll
          for (int r = 0; r < 4; ++r) np2[mt][r] += __shfl_xor(np2[mt][r], m);
      if (a == 0) {
#pragma unroll
        for (int mt = 0; mt < 2; ++mt)
#pragma unroll
          for (int r = 0; r < 4; ++r) normp_s[w][16 * mt + 4 * g + r] = np2[mt][r];
      }
    }
    WGBAR();   // barC: norm partials visible

    // ---- softmax (waves 0-3; col p = 16w + a); per-lane norm gather (no barD) ----
    if (w < 4) {
      const int hl = w >> 1;
      const int p = 16 * w + a;
      float sc[2][4];
      float cmax = -3e38f;
#pragma unroll
      for (int mt = 0; mt < 2; ++mt)
#pragma unroll
        for (int r = 0; r < 4; ++r) {
          const int t = 16 * mt + 4 * g + r;
          float n2 = normp_s[4 * hl + 0][t] + normp_s[4 * hl + 1][t]
                   + normp_s[4 * hl + 2][t] + normp_s[4 * hl + 3][t];
          float s = qacc[mt][r] * rsqrtf(fmaxf(n2, 1e-24f));
          sc[mt][r] = s;
          cmax = fmaxf(cmax, s);
        }
      cmax = fmaxf(cmax, __shfl_xor(cmax, 16));
      cmax = fmaxf(cmax, __shfl_xor(cmax, 32));
      float mo = mArr_s[p];
      float mn = fmaxf(mo, cmax);
      float fe = __expf(mo - mn);
      float ls = 0.f;
#pragma unroll
      for (int mt = 0; mt < 2; ++mt) {
        half4_t wp;
#pragma unroll
        for (int r = 0; r < 4; ++r) {
          float e = __expf(sc[mt][r] - mn);
          ls += e;
          wp[r] = (_Float16)e;
        }
        *reinterpret_cast<half4_t*>(wl_raw + p * 80 + 32 * mt + 8 * g) = wp;
      }
      ls += __shfl_xor(ls, 16);
      ls += __shfl_xor(ls, 32);
      if (l < 16) {
        mArr_s[p] = mn;
        lArr_s[p] = lArr_s[p] * fe + ls;
        fbuf_s[p] = fe;
      }
    }
    WGBAR();   // barE: wl + fbuf ready

    // ---- rescale acc + G3 ----
#pragma unroll
    for (int mA = 0; mA < 4; ++mA)
#pragma unroll
      for (int r = 0; r < 4; ++r) {
        float f = fbuf_s[16 * mA + 4 * g + r];
#pragma unroll
        for (int nt = 0; nt < 4; ++nt) acc3[mA][nt][r] *= f;
      }
    {
      half8_t wlf[4];
#pragma unroll
      for (int mA = 0; mA < 4; ++mA)
        wlf[mA] = *reinterpret_cast<const half8_t*>(wl_raw + (16 * mA + a) * 80 + 16 * g);
#pragma unroll
      for (int nt = 0; nt < 4; ++nt) {
        const int d = 64 * w + 16 * nt + a;
        const unsigned char* rowp = xt_raw + d * 72;
        const int key = (d >> 4) & 7;
        half4_t lo = *reinterpret_cast<const half4_t*>(rowp + 8 * ((2 * g) ^ key));
        half4_t hi = *reinterpret_cast<const half4_t*>(rowp + 8 * ((2 * g + 1) ^ key));
        half8_t bf;
        bf[0] = lo[0]; bf[1] = lo[1]; bf[2] = lo[2]; bf[3] = lo[3];
        bf[4] = hi[0]; bf[5] = hi[1]; bf[6] = hi[2]; bf[7] = hi[3];
#pragma unroll
        for (int mA = 0; mA < 4; ++mA) acc3[mA][nt] = MFMA(wlf[mA], bf, acc3[mA][nt]);
      }
    }
  }

  __syncthreads();
  // ---- epilogue: xbar (f16) + ml ----
#pragma unroll
  for (int mA = 0; mA < 4; ++mA)
#pragma unroll
    for (int r = 0; r < 4; ++r) {
      const int p = 16 * mA + 4 * g + r;
      const int h = 2 * g2 + (p >> 5), ph = p & 31;
      _Float16* xb = xbar + ((((size_t)b * NH + h) * NCHUNK + c) * NPAD + ph) * DDIM;
#pragma unroll
      for (int nt = 0; nt < 4; ++nt) xb[64 * w + 16 * nt + a] = (_Float16)acc3[mA][nt][r];
    }
  if (tid < 64) {
    const int h = 2 * g2 + (tid >> 5), ph = tid & 31;
    size_t mlb = ((((size_t)b * NH + h) * NCHUNK + c) * NPAD + ph) * 2;
    ml[mlb] = mArr_s[tid];
    ml[mlb + 1] = lArr_s[tid];
  }
}

// ---------------- combine chunk partials, apply Wv: one block per (b,h) ----
__global__ __launch_bounds__(256) void reduce_proto(
    const float* __restrict__ ml, const _Float16* __restrict__ xbar,
    const float* __restrict__ Wv, float* __restrict__ proto_t)
{
  const int tid = threadIdx.x;
  const int h = blockIdx.x & 3, b = blockIdx.x >> 2;

  __shared__ float fch[NCHUNK][NPAD];          // [cc][p]
  __shared__ float Linv_s[NPAD];
  __shared__ __align__(16) float xbs[NP][DDIM];  // 48 KB

  // ---- phase 1: per-p chunk combine factors (32-lane shuffle groups over cc) ----
  {
    const int cc = tid & 31;
    const int pg = (tid >> 5) & 7;   // 8 p per pass (within cc-group)
#pragma unroll
    for (int pass = 0; pass < 3; ++pass) {
      const int p = pg + 8 * pass;
      size_t idx = ((((size_t)b * NH + h) * NCHUNK + cc) * NPAD + p) * 2;
      float m = ml[idx], lv = ml[idx + 1];
      float mstar = m;
#pragma unroll
      for (int k = 1; k < 32; k <<= 1) mstar = fmaxf(mstar, __shfl_xor(mstar, k));
      float f = __expf(m - mstar);
      float Lp = lv * f;
#pragma unroll
      for (int k = 1; k < 32; k <<= 1) Lp += __shfl_xor(Lp, k);
      fch[cc][p] = f;
      if (cc == 0) Linv_s[p] = 1.f / fmaxf(Lp, 1e-30f);
    }
  }
  __syncthreads();

  // ---- phase 2: xbs[p][d] = sum_cc fch[cc][p] * xbar16[cc][p][d] ----
  for (int p = 0; p < NP; ++p) {
    float a0 = 0.f, a1 = 0.f;
#pragma unroll 4
    for (int cc = 0; cc < NCHUNK; ++cc) {
      const float f = fch[cc][p];
      const _Float16* src = xbar + ((((size_t)b * NH + h) * NCHUNK + cc) * NPAD + p) * DDIM;
      half2_t v = *reinterpret_cast<const half2_t*>(src + 2 * tid);
      a0 += f * (float)v[0];
      a1 += f * (float)v[1];
    }
    xbs[p][2 * tid] = a0;
    xbs[p][2 * tid + 1] = a1;
  }
  __syncthreads();

  // ---- phase 3: proto_t[b][p][h*128+j] = (xbs[p] . Wv[h*128+j]) * Linv[p] ----
  {
    const int j = tid & 127, pg3 = tid >> 7;   // 12 p per thread
    float accp[12];
#pragma unroll
    for (int pp = 0; pp < 12; ++pp) accp[pp] = 0.f;
    const float4* wrow = reinterpret_cast<const float4*>(Wv + (size_t)(h * HDIM + j) * DDIM);
    for (int d4 = 0; d4 < 128; ++d4) {
      float4 wv4 = wrow[d4];
#pragma unroll
      for (int pp = 0; pp < 12; ++pp) {
        float4 xv = *reinterpret_cast<const float4*>(&xbs[pg3 * 12 + pp][d4 * 4]);
        accp[pp] += wv4.x * xv.x + wv4.y * xv.y + wv4.z * xv.z + wv4.w * xv.w;
      }
    }
#pragma unroll
    for (int pp = 0; pp < 12; ++pp) {
      const int p = pg3 * 12 + pp;
      proto_t[((size_t)b * NP + p) * DDIM + h * HDIM + j] = accp[pp] * Linv_s[p];
    }
  }
}

// ---------------- proto scores, stable top-k, mean, SiLU MLP ----
__global__ __launch_bounds__(512) void final_mlp(
    const float* __restrict__ proto_t, const float* __restrict__ W1, const float* __restrict__ b1,
    const float* __restrict__ W2, const float* __restrict__ b2, float* __restrict__ out)
{
  const int b = blockIdx.x, tid = threadIdx.x;
  __shared__ float pt[NP][DDIM];
  __shared__ float spart[NP][8];
  __shared__ float sc[NP];
  __shared__ int sel[NP];
  __shared__ float zb[DDIM];
  __shared__ float hb[DDIM];
  for (int i = tid; i < NP * DDIM; i += 512) pt[i >> 9][i & 511] = proto_t[(size_t)b * NP * DDIM + i];
  __syncthreads();
  {
    int p = tid >> 3, pr = tid & 7;
    if (p < NP) {
      float s = 0.f;
      for (int k = 0; k < 64; ++k) { float v = pt[p][pr * 64 + k]; s += v * v; }
      spart[p][pr] = s;
    }
  }
  __syncthreads();
  if (tid < NP) {
    float s = 0.f;
    for (int k = 0; k < 8; ++k) s += spart[tid][k];
    sc[tid] = s;
  }
  __syncthreads();
  if (tid < NP) {
    float sv = sc[tid]; int rank = 0;
    for (int q = 0; q < NP; ++q) { float so = sc[q]; if (so > sv || (so == sv && q < tid)) ++rank; }
    sel[tid] = (rank < NTOPK) ? 1 : 0;
  }
  __syncthreads();
  {
    float z0 = 0.f;
#pragma unroll
    for (int p = 0; p < NP; ++p)
      if (sel[p]) z0 += pt[p][tid];
    zb[tid] = z0 * (1.f / NTOPK);
  }
  __syncthreads();
  {
    const float* wr = W1 + (size_t)tid * DDIM;
    float s = 0.f;
#pragma unroll 4
    for (int d = 0; d < DDIM; ++d) s += zb[d] * wr[d];
    s += b1[tid];
    hb[tid] = s / (1.f + expf(-s));
  }
  __syncthreads();
  {
    const float* wr = W2 + (size_t)tid * DDIM;
    float s = 0.f;
#pragma unroll 4
    for (int d = 0; d < DDIM; ++d) s += hb[d] * wr[d];
    out[(size_t)b * DDIM + tid] = s + b2[tid];
  }
}

extern "C" void kernel_launch(void* const* d_in, const int* in_sizes, int n_in,
                              void* d_out, int out_size, void* d_ws, size_t ws_size,
                              hipStream_t stream)
{
  const float* x    = (const float*)d_in[0];
  const float* prt  = (const float*)d_in[1];
  const float* ln_g = (const float*)d_in[2];
  const float* ln_b = (const float*)d_in[3];
  const float* Wq   = (const float*)d_in[4];
  const float* Wk   = (const float*)d_in[5];
  const float* Wv   = (const float*)d_in[6];
  const float* W1   = (const float*)d_in[7];
  const float* b1   = (const float*)d_in[8];
  const float* W2   = (const float*)d_in[9];
  const float* b2   = (const float*)d_in[10];
  float* out = (float*)d_out;
  float* ws = (float*)d_ws;

  float* qhs = ws;                       // 12288
  float* ml  = ws + 12288;               // 65536
  _Float16* xb16 = (_Float16*)(ws + 77824);      // 16777216 halves
  float* pt  = ws + 8466432;             // 98304
  _Float16* wk16  = (_Float16*)(ws + 8564736);   // 262144 halves
  _Float16* wqk16 = (_Float16*)(ws + 8695808);   // 65536 halves

  qh_kernel<<<NP, 256, 0, stream>>>(prt, Wq, qhs);
  wk16_kernel<<<512, 256, 0, stream>>>(Wk, wk16);
  wqk_kernel<<<128, 256, 0, stream>>>(qhs, Wk, wqk16);
  attn3<<<BB * 2 * NCHUNK, 512, 0, stream>>>(x, ln_g, ln_b, wk16, wqk16, ml, xb16);
  reduce_proto<<<BB * NH, 256, 0, stream>>>(ml, xb16, Wv, pt);
  final_mlp<<<BB, 512, 0, stream>>>(pt, W1, b1, W2, b2, out);
}

// Round 7
// 340.738 us; speedup vs baseline: 1.4459x; 1.4459x over previous
//
#include <hip/hip_runtime.h>
#include <hip/hip_bf16.h>

#define BB 8
#define TSEQ 8192
#define DDIM 512
#define NH 4
#define HDIM 128
#define NP 24
#define NPAD 32
#define NTOPK 12
#define NCHUNK 32
#define TCHUNK 256
#define TTILE 32
#define NTILES 8

typedef _Float16 half8_t __attribute__((ext_vector_type(8)));
typedef _Float16 half4_t __attribute__((ext_vector_type(4)));
typedef _Float16 half2_t __attribute__((ext_vector_type(2)));
typedef float f32x4_t __attribute__((ext_vector_type(4)));

#define MFMA(a, b, c) __builtin_amdgcn_mfma_f32_16x16x32_f16((a), (b), (c), 0, 0, 0)

// Barrier that does NOT drain vmcnt: LDS ordering only.
#define WGBAR() do { asm volatile("s_waitcnt lgkmcnt(0)" ::: "memory"); \
                     __builtin_amdgcn_s_barrier(); } while (0)

// ws layout (float units):
// qhs     @ 0        (12288)
// ml      @ 12288    (65536)
// xbar16  @ 77824    (16777216 f16)
// pt      @ 8466432  (98304)
// wk16    @ 8564736  (262144 f16)
// wqk16   @ 8695808  (65536 f16)
// normINV @ 8728576  (262144)  [B][H][T] f32
// total 8990720 f32 = 36 MB

// ---------------- Qh precompute ----
__global__ __launch_bounds__(256) void qh_kernel(
    const float* __restrict__ proto, const float* __restrict__ Wq, float* __restrict__ qhs)
{
  const int p = blockIdx.x, tid = threadIdx.x;
  __shared__ float prow[DDIM];
  __shared__ float qp[DDIM];
  __shared__ float np[NH][8];
  __shared__ float nb[NH];
  prow[tid] = proto[(size_t)p * DDIM + tid];
  prow[tid + 256] = proto[(size_t)p * DDIM + tid + 256];
  __syncthreads();
#pragma unroll
  for (int i = 0; i < 2; ++i) {
    int dd = tid + i * 256;
    const float4* w4 = reinterpret_cast<const float4*>(Wq + (size_t)dd * DDIM);
    const float4* p4 = reinterpret_cast<const float4*>(prow);
    float s = 0.f;
    for (int d = 0; d < 128; ++d) {
      float4 av = p4[d], bv = w4[d];
      s += av.x * bv.x + av.y * bv.y + av.z * bv.z + av.w * bv.w;
    }
    qp[dd] = s;
  }
  __syncthreads();
  {
    int hh = tid >> 3, pr = tid & 7;
    if (hh < NH) {
      float s = 0.f;
      for (int k = 0; k < 16; ++k) { float v = qp[hh * HDIM + pr * 16 + k]; s += v * v; }
      np[hh][pr] = s;
    }
  }
  __syncthreads();
  if (tid < NH) {
    float s = 0.f;
    for (int k = 0; k < 8; ++k) s += np[tid][k];
    nb[tid] = 1.f / (fmaxf(sqrtf(s), 1e-12f) * 0.07f);
  }
  __syncthreads();
#pragma unroll
  for (int i = 0; i < 2; ++i) {
    int dd = tid + i * 256;
    int hh = dd >> 7, jj = dd & 127;
    qhs[((size_t)hh * NP + p) * HDIM + jj] = qp[dd] * nb[hh];
  }
}

// ---------------- Wk -> f16 copy ----
__global__ __launch_bounds__(256) void wk16_kernel(
    const float* __restrict__ Wk, _Float16* __restrict__ wk16)
{
  const int row = blockIdx.x, tid = threadIdx.x;
  wk16[(size_t)row * 512 + tid]       = (_Float16)Wk[(size_t)row * 512 + tid];
  wk16[(size_t)row * 512 + tid + 256] = (_Float16)Wk[(size_t)row * 512 + tid + 256];
}

// ---------------- Wqk f16 ----
__global__ __launch_bounds__(256) void wqk_kernel(
    const float* __restrict__ qhs, const float* __restrict__ Wk, _Float16* __restrict__ wqk16)
{
  const int blk = blockIdx.x, tid = threadIdx.x;
  const int p = blk & 31, h = blk >> 5;
  if (p >= NP) {
    wqk16[((size_t)(h * 32 + p)) * 512 + tid] = (_Float16)0.f;
    wqk16[((size_t)(h * 32 + p)) * 512 + tid + 256] = (_Float16)0.f;
    return;
  }
  __shared__ float qv[HDIM];
  if (tid < HDIM) qv[tid] = qhs[((size_t)h * NP + p) * HDIM + tid];
  __syncthreads();
  float s0 = 0.f, s1 = 0.f;
  for (int j = 0; j < HDIM; ++j) {
    float q = qv[j];
    const float* wr = Wk + (size_t)(h * 128 + j) * 512;
    s0 += q * wr[tid];
    s1 += q * wr[tid + 256];
  }
  wqk16[((size_t)(h * 32 + p)) * 512 + tid] = (_Float16)s0;
  wqk16[((size_t)(h * 32 + p)) * 512 + tid + 256] = (_Float16)s1;
}

// ---------------- ln_norm: dense K-projection GEMM, outputs 1/||K|| only ----
// block 512 thr, 64 tokens, all 4 heads. grid = B * T/64 = 1024.
__global__ __launch_bounds__(512, 2) void ln_norm_kernel(
    const float* __restrict__ x, const float* __restrict__ ln_g, const float* __restrict__ ln_b,
    const _Float16* __restrict__ wk16, float* __restrict__ normINV)
{
  const int tid = threadIdx.x;
  const int w = tid >> 6, l = tid & 63;
  const int g = l >> 4, a = l & 15;
  const int blk = blockIdx.x;
  const int tb = blk & 127, b = blk >> 7;
  const int t0 = tb * 64;

  __shared__ __align__(16) unsigned char xs_raw[64 * 1040];   // [64 t][520 f16]
  __shared__ float normp_s[8][64];

  float4 gq[2], bq[2];
#pragma unroll
  for (int i = 0; i < 2; ++i) {
    gq[i] = reinterpret_cast<const float4*>(ln_g)[l + 64 * i];
    bq[i] = reinterpret_cast<const float4*>(ln_b)[l + 64 * i];
  }

  const float4* xc4 = reinterpret_cast<const float4*>(x) + ((size_t)(b * TSEQ + t0)) * 128;

#pragma unroll
  for (int sb = 0; sb < 2; ++sb) {
    float4 praw[4][2];
#pragma unroll
    for (int tt = 0; tt < 4; ++tt)
#pragma unroll
      for (int i = 0; i < 2; ++i)
        praw[tt][i] = xc4[(size_t)(8 * w + 4 * sb + tt) * 128 + l + 64 * i];
    float sA[4], sB[4];
#pragma unroll
    for (int tt = 0; tt < 4; ++tt) {
      float4 v0 = praw[tt][0], v1 = praw[tt][1];
      sA[tt] = (v0.x + v0.y) + (v0.z + v0.w) + (v1.x + v1.y) + (v1.z + v1.w);
      sB[tt] = (v0.x * v0.x + v0.y * v0.y) + (v0.z * v0.z + v0.w * v0.w)
             + (v1.x * v1.x + v1.y * v1.y) + (v1.z * v1.z + v1.w * v1.w);
    }
#pragma unroll
    for (int m = 1; m < 64; m <<= 1)
#pragma unroll
      for (int tt = 0; tt < 4; ++tt) { sA[tt] += __shfl_xor(sA[tt], m); sB[tt] += __shfl_xor(sB[tt], m); }
#pragma unroll
    for (int tt = 0; tt < 4; ++tt) {
      float mu = sA[tt] * (1.f / 512.f);
      float var = sB[tt] * (1.f / 512.f) - mu * mu;
      float iv = rsqrtf(var + 1e-5f);
#pragma unroll
      for (int i = 0; i < 2; ++i) {
        float4 v = praw[tt][i];
        half4_t hx;
        hx[0] = (_Float16)((v.x - mu) * iv * gq[i].x + bq[i].x);
        hx[1] = (_Float16)((v.y - mu) * iv * gq[i].y + bq[i].y);
        hx[2] = (_Float16)((v.z - mu) * iv * gq[i].z + bq[i].z);
        hx[3] = (_Float16)((v.w - mu) * iv * gq[i].w + bq[i].w);
        *reinterpret_cast<half4_t*>(xs_raw + (8 * w + 4 * sb + tt) * 1040 + 8 * l + 512 * i) = hx;
      }
    }
  }
  __syncthreads();

  // G1: wave w covers j-rows 64w..64w+63 (head = w>>1), 64 tokens
  f32x4_t kacc[4][4];
  const f32x4_t vzero = {0.f, 0.f, 0.f, 0.f};
#pragma unroll
  for (int mt = 0; mt < 4; ++mt)
#pragma unroll
    for (int nt = 0; nt < 4; ++nt) kacc[mt][nt] = vzero;

  const _Float16* wkb0 = wk16 + ((size_t)(64 * w + a)) * 512 + g * 8;
#pragma unroll
  for (int kst = 0; kst < 16; ++kst) {
    half8_t bnt[4];
#pragma unroll
    for (int nt = 0; nt < 4; ++nt)
      bnt[nt] = *reinterpret_cast<const half8_t*>(wkb0 + (size_t)nt * 16 * 512 + kst * 32);
#pragma unroll
    for (int mt = 0; mt < 4; ++mt) {
      half8_t af = *reinterpret_cast<const half8_t*>(xs_raw + (16 * mt + a) * 1040 + kst * 64 + g * 16);
#pragma unroll
      for (int nt = 0; nt < 4; ++nt) kacc[mt][nt] = MFMA(af, bnt[nt], kacc[mt][nt]);
    }
  }
  // per-token norm partials over this wave's 64 j
  {
    float np2[4][4];
#pragma unroll
    for (int mt = 0; mt < 4; ++mt)
#pragma unroll
      for (int r = 0; r < 4; ++r) {
        float s = 0.f;
#pragma unroll
        for (int nt = 0; nt < 4; ++nt) s += kacc[mt][nt][r] * kacc[mt][nt][r];
        np2[mt][r] = s;
      }
#pragma unroll
    for (int m = 1; m < 16; m <<= 1)
#pragma unroll
      for (int mt = 0; mt < 4; ++mt)
#pragma unroll
        for (int r = 0; r < 4; ++r) np2[mt][r] += __shfl_xor(np2[mt][r], m);
    if (a == 0) {
#pragma unroll
      for (int mt = 0; mt < 4; ++mt)
#pragma unroll
        for (int r = 0; r < 4; ++r) normp_s[w][16 * mt + 4 * g + r] = np2[mt][r];
    }
  }
  __syncthreads();
  if (tid < 256) {
    const int t = tid & 63, h = tid >> 6;
    float s = normp_s[2 * h][t] + normp_s[2 * h + 1][t];
    normINV[((size_t)b * NH + h) * TSEQ + t0 + t] = rsqrtf(fmaxf(s, 1e-24f));
  }
}

// ---------------- attn4: LN + scores MFMA + online softmax + MFMA accumulate ----
// block 512 thr. grid [b8][g2 2][c32]. Norms precomputed (no G1/barC).
__global__ __launch_bounds__(512, 2) void attn4(
    const float* __restrict__ x, const float* __restrict__ ln_g, const float* __restrict__ ln_b,
    const _Float16* __restrict__ wqk16, const float* __restrict__ normINV,
    float* __restrict__ ml, _Float16* __restrict__ xbar)
{
  const int tid = threadIdx.x;
  const int w = tid >> 6, l = tid & 63;
  const int g = l >> 4, a = l & 15;
  const int blk = blockIdx.x;
  const int c = blk & 31, g2 = (blk >> 5) & 1, b = blk >> 6;

  __shared__ __align__(16) unsigned char xs_raw[32 * 1040];   // [32 t][520 f16]
  __shared__ __align__(16) unsigned char xt_raw[512 * 72];    // [512 d][36 f16], quad-swizzled
  __shared__ __align__(16) unsigned char wl_raw[64 * 80];     // [64 p][40 f16]
  __shared__ float mArr_s[64], lArr_s[64], fbuf_s[64];

  if (tid < 64) { mArr_s[tid] = -1e30f; lArr_s[tid] = 0.f; }

  f32x4_t acc3[4][4];
  const f32x4_t vzero = {0.f, 0.f, 0.f, 0.f};
#pragma unroll
  for (int mA = 0; mA < 4; ++mA)
#pragma unroll
    for (int nt = 0; nt < 4; ++nt) acc3[mA][nt] = vzero;

  float4 gq[2], bq[2];
#pragma unroll
  for (int i = 0; i < 2; ++i) {
    gq[i] = reinterpret_cast<const float4*>(ln_g)[l + 64 * i];
    bq[i] = reinterpret_cast<const float4*>(ln_b)[l + 64 * i];
  }

  const float4* xc4 = reinterpret_cast<const float4*>(x) + ((size_t)(b * TSEQ + c * TCHUNK)) * 128;
  const _Float16* wqbase = wqk16 + ((size_t)(g2 * 64 + 16 * w + a)) * 512 + g * 8;   // only w<4
  const float* nbase0 = normINV + ((size_t)b * NH + 2 * g2 + (w >> 1)) * TSEQ + c * TCHUNK;

  float4 praw[4][2];
#pragma unroll
  for (int tt = 0; tt < 4; ++tt)
#pragma unroll
    for (int i = 0; i < 2; ++i)
      praw[tt][i] = xc4[(size_t)(4 * w + tt) * 128 + l + 64 * i];

  for (int tile = 0; tile < NTILES; ++tile) {
    // ---- LN stats ----
    float sA[4], sB[4];
#pragma unroll
    for (int tt = 0; tt < 4; ++tt) {
      float4 v0 = praw[tt][0], v1 = praw[tt][1];
      sA[tt] = (v0.x + v0.y) + (v0.z + v0.w) + (v1.x + v1.y) + (v1.z + v1.w);
      sB[tt] = (v0.x * v0.x + v0.y * v0.y) + (v0.z * v0.z + v0.w * v0.w)
             + (v1.x * v1.x + v1.y * v1.y) + (v1.z * v1.z + v1.w * v1.w);
    }
#pragma unroll
    for (int m = 1; m < 64; m <<= 1)
#pragma unroll
      for (int tt = 0; tt < 4; ++tt) { sA[tt] += __shfl_xor(sA[tt], m); sB[tt] += __shfl_xor(sB[tt], m); }
    float muv[4], ivv[4];
#pragma unroll
    for (int tt = 0; tt < 4; ++tt) {
      float mu = sA[tt] * (1.f / 512.f);
      float var = sB[tt] * (1.f / 512.f) - mu * mu;
      muv[tt] = mu; ivv[tt] = rsqrtf(var + 1e-5f);
    }

    WGBAR();   // barA: prev tile's GEMM reads of xs/xt done

    // ---- normalize, write xs ----
#pragma unroll
    for (int tt = 0; tt < 4; ++tt) {
#pragma unroll
      for (int i = 0; i < 2; ++i) {
        float4 v = praw[tt][i];
        v.x = (v.x - muv[tt]) * ivv[tt] * gq[i].x + bq[i].x;
        v.y = (v.y - muv[tt]) * ivv[tt] * gq[i].y + bq[i].y;
        v.z = (v.z - muv[tt]) * ivv[tt] * gq[i].z + bq[i].z;
        v.w = (v.w - muv[tt]) * ivv[tt] * gq[i].w + bq[i].w;
        praw[tt][i] = v;
        half4_t hx;
        hx[0] = (_Float16)v.x; hx[1] = (_Float16)v.y; hx[2] = (_Float16)v.z; hx[3] = (_Float16)v.w;
        *reinterpret_cast<half4_t*>(xs_raw + (4 * w + tt) * 1040 + 8 * l + 512 * i) = hx;
      }
    }
    // ---- write xt ----
    {
      const float* pf = reinterpret_cast<const float*>(praw);
#pragma unroll
      for (int i = 0; i < 2; ++i)
#pragma unroll
        for (int e = 0; e < 4; ++e) {
          half4_t hv;
          hv[0] = (_Float16)pf[0 * 8 + i * 4 + e];
          hv[1] = (_Float16)pf[1 * 8 + i * 4 + e];
          hv[2] = (_Float16)pf[2 * 8 + i * 4 + e];
          hv[3] = (_Float16)pf[3 * 8 + i * 4 + e];
          int d = 4 * l + 256 * i + e;
          *reinterpret_cast<half4_t*>(xt_raw + d * 72 + 8 * (w ^ ((d >> 4) & 7))) = hv;
        }
    }
    // ---- prefetch next tile x + this tile's norms (stay in flight across barriers) ----
    if (tile + 1 < NTILES) {
#pragma unroll
      for (int tt = 0; tt < 4; ++tt)
#pragma unroll
        for (int i = 0; i < 2; ++i)
          praw[tt][i] = xc4[(size_t)((tile + 1) * 32 + 4 * w + tt) * 128 + l + 64 * i];
    }
    f32x4_t niv4[2];
    if (w < 4) {
      const float* nb2 = nbase0 + tile * 32 + 4 * g;
      niv4[0] = *reinterpret_cast<const f32x4_t*>(nb2);
      niv4[1] = *reinterpret_cast<const f32x4_t*>(nb2 + 16);
    }
    WGBAR();   // barB: xs/xt ready

    // ---- G2 (raw scores, waves 0-3) ----
    f32x4_t qacc[2] = {vzero, vzero};
    if (w < 4) {
#pragma unroll
      for (int kst = 0; kst < 16; ++kst) {
        half8_t bq8 = *reinterpret_cast<const half8_t*>(wqbase + kst * 32);
#pragma unroll
        for (int mt = 0; mt < 2; ++mt) {
          half8_t af = *reinterpret_cast<const half8_t*>(xs_raw + (16 * mt + a) * 1040 + kst * 64 + g * 16);
          qacc[mt] = MFMA(af, bq8, qacc[mt]);
        }
      }
      // ---- softmax (col p = 16w + a) ----
      const int p = 16 * w + a;
      float sc[2][4];
      float cmax = -3e38f;
#pragma unroll
      for (int mt = 0; mt < 2; ++mt)
#pragma unroll
        for (int r = 0; r < 4; ++r) {
          float s = qacc[mt][r] * niv4[mt][r];
          sc[mt][r] = s;
          cmax = fmaxf(cmax, s);
        }
      cmax = fmaxf(cmax, __shfl_xor(cmax, 16));
      cmax = fmaxf(cmax, __shfl_xor(cmax, 32));
      float mo = mArr_s[p];
      float mn = fmaxf(mo, cmax);
      float fe = __expf(mo - mn);
      float ls = 0.f;
#pragma unroll
      for (int mt = 0; mt < 2; ++mt) {
        half4_t wp;
#pragma unroll
        for (int r = 0; r < 4; ++r) {
          float e = __expf(sc[mt][r] - mn);
          ls += e;
          wp[r] = (_Float16)e;
        }
        *reinterpret_cast<half4_t*>(wl_raw + p * 80 + 32 * mt + 8 * g) = wp;
      }
      ls += __shfl_xor(ls, 16);
      ls += __shfl_xor(ls, 32);
      if (l < 16) {
        mArr_s[p] = mn;
        lArr_s[p] = lArr_s[p] * fe + ls;
        fbuf_s[p] = fe;
      }
    }
    WGBAR();   // barE: wl + fbuf ready

    // ---- rescale acc + G3 ----
#pragma unroll
    for (int mA = 0; mA < 4; ++mA)
#pragma unroll
      for (int r = 0; r < 4; ++r) {
        float f = fbuf_s[16 * mA + 4 * g + r];
#pragma unroll
        for (int nt = 0; nt < 4; ++nt) acc3[mA][nt][r] *= f;
      }
    {
      half8_t wlf[4];
#pragma unroll
      for (int mA = 0; mA < 4; ++mA)
        wlf[mA] = *reinterpret_cast<const half8_t*>(wl_raw + (16 * mA + a) * 80 + 16 * g);
#pragma unroll
      for (int nt = 0; nt < 4; ++nt) {
        const int d = 64 * w + 16 * nt + a;
        const unsigned char* rowp = xt_raw + d * 72;
        const int key = (d >> 4) & 7;
        half4_t lo = *reinterpret_cast<const half4_t*>(rowp + 8 * ((2 * g) ^ key));
        half4_t hi = *reinterpret_cast<const half4_t*>(rowp + 8 * ((2 * g + 1) ^ key));
        half8_t bf;
        bf[0] = lo[0]; bf[1] = lo[1]; bf[2] = lo[2]; bf[3] = lo[3];
        bf[4] = hi[0]; bf[5] = hi[1]; bf[6] = hi[2]; bf[7] = hi[3];
#pragma unroll
        for (int mA = 0; mA < 4; ++mA) acc3[mA][nt] = MFMA(wlf[mA], bf, acc3[mA][nt]);
      }
    }
  }

  __syncthreads();
#pragma unroll
  for (int mA = 0; mA < 4; ++mA)
#pragma unroll
    for (int r = 0; r < 4; ++r) {
      const int p = 16 * mA + 4 * g + r;
      const int h = 2 * g2 + (p >> 5), ph = p & 31;
      _Float16* xb = xbar + ((((size_t)b * NH + h) * NCHUNK + c) * NPAD + ph) * DDIM;
#pragma unroll
      for (int nt = 0; nt < 4; ++nt) xb[64 * w + 16 * nt + a] = (_Float16)acc3[mA][nt][r];
    }
  if (tid < 64) {
    const int h = 2 * g2 + (tid >> 5), ph = tid & 31;
    size_t mlb = ((((size_t)b * NH + h) * NCHUNK + c) * NPAD + ph) * 2;
    ml[mlb] = mArr_s[tid];
    ml[mlb + 1] = lArr_s[tid];
  }
}

// ---------------- combine chunk partials, apply Wv (r5 proven version) ----
__global__ __launch_bounds__(256) void reduce_proto(
    const float* __restrict__ ml, const _Float16* __restrict__ xbar,
    const float* __restrict__ Wv, float* __restrict__ proto_t)
{
  const int tid = threadIdx.x;
  const int blk = blockIdx.x;
  const int p = blk % NP;
  const int h = (blk / NP) % NH;
  const int b = blk / (NP * NH);

  __shared__ float fch[NCHUNK];
  __shared__ float LinvS;
  __shared__ float xbs[DDIM];
  __shared__ float part[256];

  if (tid < NCHUNK) {
    size_t idx = ((((size_t)b * NH + h) * NCHUNK + tid) * NPAD + p) * 2;
    float m = ml[idx], lv = ml[idx + 1];
    float mstar = m;
#pragma unroll
    for (int k = 16; k >= 1; k >>= 1) mstar = fmaxf(mstar, __shfl_xor(mstar, k));
    float f = __expf(m - mstar);
    float Lp = lv * f;
#pragma unroll
    for (int k = 16; k >= 1; k >>= 1) Lp += __shfl_xor(Lp, k);
    fch[tid] = f;
    if (tid == 0) LinvS = 1.f / fmaxf(Lp, 1e-30f);
  }
  __syncthreads();
  float a0 = 0.f, a1 = 0.f;
  for (int cc = 0; cc < NCHUNK; ++cc) {
    float f = fch[cc];
    const _Float16* src = xbar + ((((size_t)b * NH + h) * NCHUNK + cc) * NPAD + p) * DDIM;
    half2_t v = *reinterpret_cast<const half2_t*>(src + 2 * tid);
    a0 += f * (float)v[0];
    a1 += f * (float)v[1];
  }
  xbs[2 * tid] = a0;
  xbs[2 * tid + 1] = a1;
  __syncthreads();
  const float Linv = LinvS;
  const int j = tid & 127, halfsel = tid >> 7;
  const float* wrow = Wv + (size_t)(h * HDIM + j) * DDIM + halfsel * 256;
  const float* xh = &xbs[halfsel * 256];
  float s = 0.f;
#pragma unroll 4
  for (int d = 0; d < 256; ++d) s += xh[d] * wrow[d];
  part[tid] = s;
  __syncthreads();
  if (tid < 128) {
    proto_t[((size_t)b * NP + p) * DDIM + h * HDIM + tid] = (part[tid] + part[tid + 128]) * Linv;
  }
}

// ---------------- proto scores, stable top-k, mean, SiLU MLP ----
__global__ __launch_bounds__(512) void final_mlp(
    const float* __restrict__ proto_t, const float* __restrict__ W1, const float* __restrict__ b1,
    const float* __restrict__ W2, const float* __restrict__ b2, float* __restrict__ out)
{
  const int b = blockIdx.x, tid = threadIdx.x;
  __shared__ float pt[NP][DDIM];
  __shared__ float spart[NP][8];
  __shared__ float sc[NP];
  __shared__ int sel[NP];
  __shared__ float zb[DDIM];
  __shared__ float hb[DDIM];
  for (int i = tid; i < NP * DDIM; i += 512) pt[i >> 9][i & 511] = proto_t[(size_t)b * NP * DDIM + i];
  __syncthreads();
  {
    int p = tid >> 3, pr = tid & 7;
    if (p < NP) {
      float s = 0.f;
      for (int k = 0; k < 64; ++k) { float v = pt[p][pr * 64 + k]; s += v * v; }
      spart[p][pr] = s;
    }
  }
  __syncthreads();
  if (tid < NP) {
    float s = 0.f;
    for (int k = 0; k < 8; ++k) s += spart[tid][k];
    sc[tid] = s;
  }
  __syncthreads();
  if (tid < NP) {
    float sv = sc[tid]; int rank = 0;
    for (int q = 0; q < NP; ++q) { float so = sc[q]; if (so > sv || (so == sv && q < tid)) ++rank; }
    sel[tid] = (rank < NTOPK) ? 1 : 0;
  }
  __syncthreads();
  {
    float z0 = 0.f;
#pragma unroll
    for (int p = 0; p < NP; ++p)
      if (sel[p]) z0 += pt[p][tid];
    zb[tid] = z0 * (1.f / NTOPK);
  }
  __syncthreads();
  {
    const float* wr = W1 + (size_t)tid * DDIM;
    float s = 0.f;
#pragma unroll 4
    for (int d = 0; d < DDIM; ++d) s += zb[d] * wr[d];
    s += b1[tid];
    hb[tid] = s / (1.f + expf(-s));
  }
  __syncthreads();
  {
    const float* wr = W2 + (size_t)tid * DDIM;
    float s = 0.f;
#pragma unroll 4
    for (int d = 0; d < DDIM; ++d) s += hb[d] * wr[d];
    out[(size_t)b * DDIM + tid] = s + b2[tid];
  }
}

extern "C" void kernel_launch(void* const* d_in, const int* in_sizes, int n_in,
                              void* d_out, int out_size, void* d_ws, size_t ws_size,
                              hipStream_t stream)
{
  const float* x    = (const float*)d_in[0];
  const float* prt  = (const float*)d_in[1];
  const float* ln_g = (const float*)d_in[2];
  const float* ln_b = (const float*)d_in[3];
  const float* Wq   = (const float*)d_in[4];
  const float* Wk   = (const float*)d_in[5];
  const float* Wv   = (const float*)d_in[6];
  const float* W1   = (const float*)d_in[7];
  const float* b1   = (const float*)d_in[8];
  const float* W2   = (const float*)d_in[9];
  const float* b2   = (const float*)d_in[10];
  float* out = (float*)d_out;
  float* ws = (float*)d_ws;

  float* qhs = ws;                                // 12288
  float* ml  = ws + 12288;                        // 65536
  _Float16* xb16 = (_Float16*)(ws + 77824);       // 16777216 halves
  float* pt  = ws + 8466432;                      // 98304
  _Float16* wk16  = (_Float16*)(ws + 8564736);    // 262144 halves
  _Float16* wqk16 = (_Float16*)(ws + 8695808);    // 65536 halves
  float* normINV  = ws + 8728576;                 // 262144

  qh_kernel<<<NP, 256, 0, stream>>>(prt, Wq, qhs);
  wk16_kernel<<<512, 256, 0, stream>>>(Wk, wk16);
  wqk_kernel<<<128, 256, 0, stream>>>(qhs, Wk, wqk16);
  ln_norm_kernel<<<BB * 128, 512, 0, stream>>>(x, ln_g, ln_b, wk16, normINV);
  attn4<<<BB * 2 * NCHUNK, 512, 0, stream>>>(x, ln_g, ln_b, wqk16, normINV, ml, xb16);
  reduce_proto<<<BB * NH * NP, 256, 0, stream>>>(ml, xb16, Wv, pt);
  final_mlp<<<BB, 512, 0, stream>>>(pt, W1, b1, W2, b2, out);
}